// Round 7
// baseline (128.471 us; speedup 1.0000x reference)
//
#include <hip/hip_runtime.h>

// MoGeSampledLocalLoss: per-patch truncated robust affine depth alignment +
// smooth-L1 loss, global mean over valid patches.
//
// Structure: one patch per DPP ROW (16 lanes, 16 px/lane, 4 patches/wave);
// row reductions = 4 fused DPP row_ror adds (total lands in all 16 lanes,
// no readlane). R7 changes vs R6 (~28us kernel, latency-exposure-bound:
// VALU issue only ~3.4us of it):
//  - grid halved to 1024 blocks; each wave runs 2 patch-group iterations
//    with software PREFETCH of the next group's 192B/lane, overlapping one
//    full memory-latency window with compute.
//  - global reduction: per-block PRIVATE slot line + plain stores (kernel
//    boundary orders them before finalize) -> no atomics, no memset node
//    (3 graph nodes -> 2).
// History: R1-R4 pinned at 43-47us by 65k same-line device atomics;
// R5 scatter-slots -> ~29us; R6 row-DPP instruction cut -> neutral (proved
// not issue-bound). Harness fixed cost (~100us: 256MB d_ws poison fill at
// ~40us + input restores) is not addressable from the kernel.

#define WPB 4        // waves per 256-thread block
#define PPW 4        // patches per wave (one per DPP row)
#define MAXBLK 1024  // 2 prefetched iterations per wave at 32768 patches

// Full-wave sum -> wave-uniform scalar (DPP row_shr + row_bcast + readlane).
__device__ __forceinline__ float wredu(float v) {
#define DPP_ADD(ctrl)                                                        \
  v += __int_as_float(__builtin_amdgcn_update_dpp(                           \
      0, __float_as_int(v), (ctrl), 0xf, 0xf, true))
  DPP_ADD(0x111);  // row_shr:1
  DPP_ADD(0x112);  // row_shr:2
  DPP_ADD(0x114);  // row_shr:4
  DPP_ADD(0x118);  // row_shr:8
  DPP_ADD(0x142);  // row_bcast:15
  DPP_ADD(0x143);  // row_bcast:31
#undef DPP_ADD
  return __int_as_float(__builtin_amdgcn_readlane(__float_as_int(v), 63));
}

// Sum across the 16 lanes of each DPP row; EVERY lane of the row ends with
// the row total (rotation-add is a circulant reduction: spans 2,4,8,16).
__device__ __forceinline__ float rowredu(float v) {
#define DPP_ADD(ctrl)                                                        \
  v += __int_as_float(__builtin_amdgcn_update_dpp(                           \
      0, __float_as_int(v), (ctrl), 0xf, 0xf, true))
  DPP_ADD(0x121);  // row_ror:1
  DPP_ADD(0x122);  // row_ror:2
  DPP_ADD(0x124);  // row_ror:4
  DPP_ADD(0x128);  // row_ror:8
#undef DPP_ADD
  return v;
}

__device__ __forceinline__ float frcp(float x) {
  return __builtin_amdgcn_rcpf(x);   // ~1 ulp, 1 VALU instr
}

__global__ __launch_bounds__(256) void moge_patch_kernel(
    const float* __restrict__ xg,   // pred_depth (B*N)
    const float* __restrict__ yg,   // gt_depth   (B*N)
    const int*   __restrict__ mg,   // mask       (B*N), 0/1
    const float* __restrict__ gsg,  // global_scale (B)
    const int*   __restrict__ pP,   // num_patches (device scalar)
    const int*   __restrict__ pK,   // patch_pixel_count (device scalar)
    int B,
    float* __restrict__ ws) {       // block b owns line ws[b*32 .. b*32+31]
  const int P = pP[0];
  const int K = pK[0];
  const int lane = threadIdx.x & 63;
  const int wib  = threadIdx.x >> 6;
  const int total_patches = B * P;
  const float invK = 1.0f / (float)K;

  float wloss = 0.f, wcnt = 0.f;    // per-lane accumulators

  if (K == 256) {
    // ------- fast path: patch-per-row, 16 pixels/lane, prefetched -----
    const int row = lane >> 4;       // 0..3 -> patch within wave
    const int col = lane & 15;       // lane within row
    const int poff = col * 16;       // this lane's 16-pixel chunk
    const int wave_stride = gridDim.x * WPB * PPW;

    int pbase = (blockIdx.x * WPB + wib) * PPW;
    if (pbase < total_patches) {
      float4 xa[4], ya[4]; int4 ma[4];
      {
        const int patch0 = pbase + row;
        const long base =
            ((patch0 < total_patches) ? (long)patch0 * 256L : 0L) + poff;
        #pragma unroll
        for (int j = 0; j < 4; ++j) {
          xa[j] = *(const float4*)(xg + base + 4 * j);
          ya[j] = *(const float4*)(yg + base + 4 * j);
          ma[j] = *(const int4*)(mg + base + 4 * j);
        }
      }

      for (;;) {
        // -- prefetch next patch-group (clamped, branch-free) ----------
        const int nbase_p = pbase + wave_stride;
        const bool has_next = nbase_p < total_patches;
        float4 nxa[4], nya[4]; int4 nma[4];
        {
          const int np = nbase_p + row;
          const long nb =
              ((has_next && np < total_patches) ? (long)np * 256L : 0L) + poff;
          #pragma unroll
          for (int j = 0; j < 4; ++j) {
            nxa[j] = *(const float4*)(xg + nb + 4 * j);
            nya[j] = *(const float4*)(yg + nb + 4 * j);
            nma[j] = *(const int4*)(mg + nb + 4 * j);
          }
        }

        const int patch = pbase + row;
        const bool row_ok = patch < total_patches;
        const float* xr = (const float*)xa;
        const float* yr = (const float*)ya;
        const int*   mi = (const int*)ma;
        float wv[16];

        // -- pass 1: WLS sums (msum/symsum reduced with batch 2) -------
        float sw = 0.f, swx = 0.f, swy = 0.f, swxx = 0.f, swxy = 0.f;
        float msum = 0.f, symsum = 0.f;
        #pragma unroll
        for (int i = 0; i < 16; ++i) {
          const float m = mi[i] ? 1.f : 0.f;
          const float xx = xr[i], yy = yr[i];
          const float w = m * frcp(fmaxf(yy, 1e-5f));
          wv[i] = w;
          const float wx = w * xx;
          sw += w; swx += wx; swy = fmaf(w, yy, swy);
          swxx = fmaf(wx, xx, swxx); swxy = fmaf(wx, yy, swxy);
          msum += m; symsum = fmaf(m, yy, symsum);
        }
        sw = rowredu(sw); swx = rowredu(swx); swy = rowredu(swy);
        swxx = rowredu(swxx); swxy = rowredu(swxy);

        float det = sw * swxx - swx * swx;
        if (fabsf(det) < 1e-12f) det = 1e-12f;  // jnp.where -> +1e-12 any sign
        float rdet = frcp(det);
        const float s0 = (sw * swxy - swx * swy) * rdet;
        const float t0 = (swxx * swy - swx * swxy) * rdet;

        // -- pass 2: truncated refit (+ deferred mask stats) -----------
        float sw2 = 0.f, swx2 = 0.f, swy2 = 0.f, swxx2 = 0.f, swxy2 = 0.f;
        #pragma unroll
        for (int i = 0; i < 16; ++i) {
          const float xx = xr[i], yy = yr[i], w = wv[i];
          const float e = w * fabsf(fmaf(s0, xx, t0) - yy);
          const float w2 = (e < 1.0f) ? w : 0.f;  // TRUNC = 1.0, strict <
          const float w2x = w2 * xx;
          sw2 += w2; swx2 += w2x; swy2 = fmaf(w2, yy, swy2);
          swxx2 = fmaf(w2x, xx, swxx2); swxy2 = fmaf(w2x, yy, swxy2);
        }
        sw2 = rowredu(sw2); swx2 = rowredu(swx2); swy2 = rowredu(swy2);
        swxx2 = rowredu(swxx2); swxy2 = rowredu(swxy2);
        msum = rowredu(msum); symsum = rowredu(symsum);

        if (sw2 > 1e-8f) {  // sum(w2)==sw2; else fall back to pass-1 sums
          sw = sw2; swx = swx2; swy = swy2; swxx = swxx2; swxy = swxy2;
        }
        det = sw * swxx - swx * swx;
        if (fabsf(det) < 1e-12f) det = 1e-12f;
        rdet = frcp(det);
        const float s = (sw * swxy - swx * swy) * rdet;
        const float t = (swxx * swy - swx * swxy) * rdet;

        // -- pass 3: smooth-L1 patch loss ------------------------------
        const float mean_depth =
            (msum > 0.f) ? (symsum * frcp(fmaxf(msum, 1.f))) : 1.f;
        const float yfloor = 0.1f * mean_depth;

        float lsum = 0.f;
        #pragma unroll
        for (int i = 0; i < 16; ++i) {
          const float m = (wv[i] > 0.f) ? 1.f : 0.f;  // recover mask from w
          const float pw = m * frcp(fmaxf(yr[i], yfloor));
          const float err = fabsf(fmaf(s, xr[i], t) - yr[i]) * pw;
          // BETA = 0.1: err<0.1 ? 0.5*err^2/0.1 : err-0.05
          lsum += (err < 0.1f) ? (5.0f * err * err) : (err - 0.05f);
        }
        const float patch_loss = rowredu(lsum) * invK;

        // -- validity (row-uniform), accumulate on col==0 --------------
        const int pidx = row_ok ? patch : (total_patches - 1);
        const float gs = gsg[(unsigned)pidx / (unsigned)P];
        const float ratio = s * frcp(fmaxf(gs, 1e-12f));
        const bool gs_ok = (gs > 0.f) ? (ratio >= 0.1f && ratio <= 10.0f) : true;
        const bool valid = (msum * invK >= 0.3f) && (s > 0.f) && gs_ok;

        if (col == 0 && row_ok && valid) { wloss += patch_loss; wcnt += 1.f; }

        if (!has_next) break;
        pbase = nbase_p;
        #pragma unroll
        for (int j = 0; j < 4; ++j) { xa[j] = nxa[j]; ya[j] = nya[j]; ma[j] = nma[j]; }
      }
    }
  } else {
    // ------- generic path (any K): wave-per-patch ---------------------
    const int wave_stride = gridDim.x * WPB;
    for (int patch = blockIdx.x * WPB + wib; patch < total_patches;
         patch += wave_stride) {
      const long base = (long)patch * (long)K;
      const float* xp = xg + base;
      const float* yp = yg + base;
      const int*   mp = mg + base;

      float sw = 0.f, swx = 0.f, swy = 0.f, swxx = 0.f, swxy = 0.f;
      float msum = 0.f, symsum = 0.f;
      for (int j = lane; j < K; j += 64) {
        const float m = mp[j] ? 1.f : 0.f;
        const float xx = xp[j], yy = yp[j];
        const float w = m * frcp(fmaxf(yy, 1e-5f));
        const float wx = w * xx;
        sw += w; swx += wx; swy = fmaf(w, yy, swy);
        swxx = fmaf(wx, xx, swxx); swxy = fmaf(wx, yy, swxy);
        msum += m; symsum = fmaf(m, yy, symsum);
      }
      sw = wredu(sw); swx = wredu(swx); swy = wredu(swy);
      swxx = wredu(swxx); swxy = wredu(swxy);
      msum = wredu(msum); symsum = wredu(symsum);

      float det = sw * swxx - swx * swx;
      if (fabsf(det) < 1e-12f) det = 1e-12f;
      float rdet = frcp(det);
      const float s0 = (sw * swxy - swx * swy) * rdet;
      const float t0 = (swxx * swy - swx * swxy) * rdet;

      float sw2 = 0.f, swx2 = 0.f, swy2 = 0.f, swxx2 = 0.f, swxy2 = 0.f;
      for (int j = lane; j < K; j += 64) {
        const float m = mp[j] ? 1.f : 0.f;
        const float xx = xp[j], yy = yp[j];
        const float w = m * frcp(fmaxf(yy, 1e-5f));
        const float e = w * fabsf(fmaf(s0, xx, t0) - yy);
        const float w2 = (e < 1.0f) ? w : 0.f;
        const float w2x = w2 * xx;
        sw2 += w2; swx2 += w2x; swy2 = fmaf(w2, yy, swy2);
        swxx2 = fmaf(w2x, xx, swxx2); swxy2 = fmaf(w2x, yy, swxy2);
      }
      sw2 = wredu(sw2); swx2 = wredu(swx2); swy2 = wredu(swy2);
      swxx2 = wredu(swxx2); swxy2 = wredu(swxy2);

      if (sw2 > 1e-8f) {
        sw = sw2; swx = swx2; swy = swy2; swxx = swxx2; swxy = swxy2;
      }
      det = sw * swxx - swx * swx;
      if (fabsf(det) < 1e-12f) det = 1e-12f;
      rdet = frcp(det);
      const float s = (sw * swxy - swx * swy) * rdet;
      const float t = (swxx * swy - swx * swxy) * rdet;

      const float mean_depth =
          (msum > 0.f) ? (symsum * frcp(fmaxf(msum, 1.f))) : 1.f;
      const float yfloor = 0.1f * mean_depth;

      float lsum = 0.f;
      for (int j = lane; j < K; j += 64) {
        const float m = mp[j] ? 1.f : 0.f;
        const float xx = xp[j], yy = yp[j];
        const float pw = m * frcp(fmaxf(yy, yfloor));
        const float err = fabsf(fmaf(s, xx, t) - yy) * pw;
        lsum += (err < 0.1f) ? (5.0f * err * err) : (err - 0.05f);
      }
      const float patch_loss = wredu(lsum) * invK;

      const float gs = gsg[(unsigned)patch / (unsigned)P];
      const float ratio = s * frcp(fmaxf(gs, 1e-12f));
      const bool gs_ok = (gs > 0.f) ? (ratio >= 0.1f && ratio <= 10.0f) : true;
      const bool valid = (msum * invK >= 0.3f) && (s > 0.f) && gs_ok;

      if (lane == 0 && valid) { wloss += patch_loss; wcnt += 1.f; }
    }
  }

  // ---- wave reduce -> block reduce (LDS) -> plain store to OWN line --
  wloss = wredu(wloss);
  wcnt  = wredu(wcnt);
  __shared__ float sl[WPB], sc[WPB];
  if (lane == 0) { sl[wib] = wloss; sc[wib] = wcnt; }
  __syncthreads();
  if (threadIdx.x == 0) {
    float bl = 0.f, bc = 0.f;
    #pragma unroll
    for (int i = 0; i < WPB; ++i) { bl += sl[i]; bc += sc[i]; }
    // private 128-B line per block: no zeroing, no atomics needed.
    ws[blockIdx.x * 32]     = bl;
    ws[blockIdx.x * 32 + 1] = bc;
  }
}

__global__ __launch_bounds__(256) void finalize_kernel(
    const float* __restrict__ ws, float* __restrict__ out, int nblocks) {
  const int lane = threadIdx.x & 63;
  const int wib  = threadIdx.x >> 6;
  float l = 0.f, c = 0.f;
  for (int i = threadIdx.x; i < nblocks; i += 256) {
    l += ws[i * 32];
    c += ws[i * 32 + 1];
  }
  l = wredu(l); c = wredu(c);
  __shared__ float sl[4], sc[4];
  if (lane == 0) { sl[wib] = l; sc[wib] = c; }
  __syncthreads();
  if (threadIdx.x == 0) {
    const float L = sl[0] + sl[1] + sl[2] + sl[3];
    const float C = sc[0] + sc[1] + sc[2] + sc[3];
    out[0] = (C > 0.f) ? (L / fmaxf(C, 1.f)) : 0.f;
  }
}

extern "C" void kernel_launch(void* const* d_in, const int* in_sizes, int n_in,
                              void* d_out, int out_size, void* d_ws, size_t ws_size,
                              hipStream_t stream) {
  const float* pred = (const float*)d_in[0];
  const float* gt   = (const float*)d_in[1];
  const int*   mask = (const int*)d_in[2];
  const float* gs   = (const float*)d_in[3];
  const int*   pP   = (const int*)d_in[4];
  const int*   pK   = (const int*)d_in[5];
  const int B = in_sizes[3];
  const long total_pixels = (long)in_sizes[0];
  float* ws = (float*)d_ws;

  // grid sized for K=256: 16 patches/block/iter; <=MAXBLK -> 2 prefetched
  // iterations per wave at the reference shape (32768 patches).
  long est_patches = total_pixels / 256;
  long blocks = (est_patches + WPB * PPW - 1) / (WPB * PPW);
  if (blocks < 1) blocks = 1;
  if (blocks > MAXBLK) blocks = MAXBLK;
  moge_patch_kernel<<<(int)blocks, 256, 0, stream>>>(pred, gt, mask, gs, pP,
                                                     pK, B, ws);
  finalize_kernel<<<1, 256, 0, stream>>>(ws, (float*)d_out, (int)blocks);
}